// Round 8
// baseline (513.435 us; speedup 1.0000x reference)
//
#include <hip/hip_runtime.h>
#include <hip/hip_bf16.h>
#include <math.h>

// Problem constants
#define B_ 4
#define N_ 2048
#define D_ 512
#define H_ 8
#define DH_ 128
#define INNER_ 1024   // H_*DH_
#define W_ 32         // gaussian window half-width; exp(-33^2/(2*2.5^2)) ~ 1e-38
#define M_ (B_ * N_)  // 8192
#define GRID_ 1024    // 4 blocks/CU x 256 CU -> all co-resident (LB(256,4), LDS 17.4K)

typedef __attribute__((ext_vector_type(8))) short short8;
typedef __attribute__((ext_vector_type(4))) float floatx4;

typedef const __attribute__((address_space(1))) char* gcp;
typedef __attribute__((address_space(3))) char* lcp;

__device__ __forceinline__ float bf16hi_to_f(unsigned u) {
    union { unsigned u; float f; } c; c.u = u; return c.f;
}

// ---------------------------------------------------------------------------
// Device-wide full-arrival barrier. Safe because grid==1024 is guaranteed
// fully resident (see launch config). Counter zeroed by hipMemsetAsync
// before each kernel launch (fresh per graph replay).
// ---------------------------------------------------------------------------
__device__ __forceinline__ void gbar(unsigned* c) {
    __syncthreads();
    if (threadIdx.x == 0) {
        __threadfence();   // make prior global writes device-visible
        __hip_atomic_fetch_add(c, 1u, __ATOMIC_ACQ_REL, __HIP_MEMORY_SCOPE_AGENT);
        while (__hip_atomic_load(c, __ATOMIC_ACQUIRE, __HIP_MEMORY_SCOPE_AGENT) < GRID_)
            __builtin_amdgcn_s_sleep(1);
        __threadfence();   // invalidate stale cached lines before phase reads
    }
    __syncthreads();
}

// ---------------------------------------------------------------------------
// 32x32 fp32 -> bf16 transpose tile (uses first 4.2 KB of smem)
// ---------------------------------------------------------------------------
__device__ __forceinline__ void transpose32(
    const float* __restrict__ src, __hip_bfloat16* __restrict__ dst,
    int R, int Cn, int rt, int ct, int tid, char* smem)
{
    float (*t)[33] = (float(*)[33])smem;
    int c0 = ct * 32, r0 = rt * 32;
    int lx = tid & 31, ly = tid >> 5;   // 32 x 8
    #pragma unroll
    for (int i = 0; i < 32; i += 8)
        t[ly + i][lx] = src[(size_t)(r0 + ly + i) * Cn + c0 + lx];
    __syncthreads();
    #pragma unroll
    for (int i = 0; i < 32; i += 8)
        dst[(size_t)(c0 + ly + i) * R + r0 + lx] = __float2bfloat16(t[lx][ly + i]);
    __syncthreads();
}

// ---------------------------------------------------------------------------
// One 64x64 bf16-MFMA GEMM tile, BK=64 (r7 structure): A[M,K] rm, Bt[N,K].
// smem: Asm 8K | Bsm 8K, reused as Cs 16K in epilogue. Trailing sync so the
// caller may immediately reuse smem.
// ---------------------------------------------------------------------------
template <typename OutT>
__device__ __forceinline__ void gemm_tile(
    const __hip_bfloat16* __restrict__ A, const __hip_bfloat16* __restrict__ Bt,
    OutT* __restrict__ C, int N, int K, int bm, int bn, int tid, char* smem)
{
    __hip_bfloat16* Asm = (__hip_bfloat16*)smem;
    __hip_bfloat16* Bsm = (__hip_bfloat16*)(smem + 8192);

    const int lane = tid & 63;
    const int w    = tid >> 6;
    const int wm   = w >> 1;
    const int wn   = w & 1;
    const int kh   = lane >> 4;
    const int ml   = lane & 15;

    floatx4 acc[2][2];
    #pragma unroll
    for (int i = 0; i < 2; ++i)
        #pragma unroll
        for (int j = 0; j < 2; ++j) acc[i][j] = (floatx4){0.f, 0.f, 0.f, 0.f};

    const char* Ab = (const char*)(A + (size_t)(bm * 64) * K);
    const char* Bb = (const char*)(Bt + (size_t)(bn * 64) * K);
    const size_t rowstride = (size_t)K * 2;

    for (int k0 = 0; k0 < K; k0 += 64) {
        #pragma unroll
        for (int it = 0; it < 2; ++it) {
            int o = it * 4096 + tid * 16;   // wave-uniform base + lane*16
            int r = o >> 7;                 // tile row 0..63
            int s = (o >> 4) & 7;
            int c = s ^ (r & 7);            // XOR-row chunk swizzle
            size_t goff = (size_t)r * rowstride + (size_t)k0 * 2 + c * 16;
            __builtin_amdgcn_global_load_lds((gcp)(Ab + goff), (lcp)((char*)Asm + o), 16, 0, 0);
            __builtin_amdgcn_global_load_lds((gcp)(Bb + goff), (lcp)((char*)Bsm + o), 16, 0, 0);
        }
        __syncthreads();

        const short* As = (const short*)Asm;
        const short* Bs = (const short*)Bsm;
        short8 af[2][2], bf[2][2];
        #pragma unroll
        for (int t = 0; t < 2; ++t) {
            int ra = wm * 32 + t * 16 + ml;
            int rb = wn * 32 + t * 16 + ml;
            #pragma unroll
            for (int kk = 0; kk < 2; ++kk) {
                int ch = kk * 4 + kh;
                af[t][kk] = *(const short8*)(As + ra * 64 + ((ch ^ (ra & 7)) * 8));
                bf[t][kk] = *(const short8*)(Bs + rb * 64 + ((ch ^ (rb & 7)) * 8));
            }
        }
        #pragma unroll
        for (int kk = 0; kk < 2; ++kk)
            #pragma unroll
            for (int i = 0; i < 2; ++i)
                #pragma unroll
                for (int j = 0; j < 2; ++j)
                    acc[i][j] = __builtin_amdgcn_mfma_f32_16x16x32_bf16(
                        af[i][kk], bf[j][kk], acc[i][j], 0, 0, 0);
        __syncthreads();
    }

    // epilogue via LDS for vector stores
    float* Cs = (float*)smem;
    const int rq = lane >> 4;
    const int cl = lane & 15;
    #pragma unroll
    for (int i = 0; i < 2; ++i)
        #pragma unroll
        for (int j = 0; j < 2; ++j)
            #pragma unroll
            for (int r = 0; r < 4; ++r)
                Cs[(wm * 32 + i * 16 + rq * 4 + r) * 64 + wn * 32 + j * 16 + cl] = acc[i][j][r];
    __syncthreads();

    if constexpr (sizeof(OutT) == 2) {
        #pragma unroll
        for (int p = 0; p < 2; ++p) {
            int idx = p * 256 + tid;
            int rr = idx >> 3;
            int cc = (idx & 7) * 8;
            const float* src = Cs + rr * 64 + cc;
            __hip_bfloat16 o[8];
            #pragma unroll
            for (int e = 0; e < 8; ++e) o[e] = __float2bfloat16(src[e]);
            *(short8*)((__hip_bfloat16*)C + (size_t)(bm * 64 + rr) * N + bn * 64 + cc) = *(short8*)o;
        }
    } else {
        #pragma unroll
        for (int p = 0; p < 4; ++p) {
            int idx = p * 256 + tid;
            int rr = idx >> 4;
            int cc = (idx & 15) * 4;
            float4 vv = *(const float4*)(Cs + rr * 64 + cc);
            *(float4*)((float*)C + (size_t)(bm * 64 + rr) * N + bn * 64 + cc) = vv;
        }
    }
    __syncthreads();   // protect smem for caller reuse
}

// ---------------------------------------------------------------------------
// One banded-gaussian-blur job (r7 banded_attn3 structure).
// job = ((b*16 + y) * 32 + ntile), y = h*2 + chhalf. smem >= 16900 B.
// ---------------------------------------------------------------------------
#define TNA 64
#define ROWSB (TNA + 2 * W_)   // 128
#define CHB 64

struct bf16x4s { __hip_bfloat16 a, b, c, d; };

__device__ __forceinline__ void blur_tile(
    const __hip_bfloat16* __restrict__ v, const float* __restrict__ sigma,
    __hip_bfloat16* __restrict__ attn, int job, int tid, char* smem)
{
    __hip_bfloat16 (*vs)[CHB] = (__hip_bfloat16(*)[CHB])smem;   // 16 KB
    float* wtab = (float*)(smem + 16384);                       // 65 floats
    float* winv = wtab + 68;                                    // 64 floats

    const int b   = job >> 9;
    const int y   = (job >> 5) & 15;
    const int n0  = (job & 31) * TNA;
    const int h   = y >> 1;
    const int ch0 = (y & 1) * CHB;

    const __hip_bfloat16* vbase = v + (size_t)b * N_ * INNER_ + h * DH_ + ch0;
    #pragma unroll
    for (int it = 0; it < 4; ++it) {
        int idx = tid + it * 256;     // 0..1023
        int r = idx >> 3;             // 0..127
        int g = idx & 7;
        int m = n0 - W_ + r;
        int4 val = make_int4(0, 0, 0, 0);
        if (m >= 0 && m < N_) val = *(const int4*)(vbase + (size_t)m * INNER_ + g * 8);
        *(int4*)&vs[r][g * 8] = val;
    }
    if (tid <= 2 * W_) {
        float sig = sigma[h];
        float d = (float)(tid - W_);
        wtab[tid] = __expf(-d * d / (2.0f * sig * sig));
    }
    __syncthreads();

    if (tid < TNA) {
        int n = n0 + tid;
        float ws = 0.f;
        #pragma unroll
        for (int j = 0; j <= 2 * W_; ++j) {
            int m = n - W_ + j;
            ws += (m >= 0 && m < N_) ? wtab[j] : 0.f;
        }
        winv[tid] = 1.0f / ws;
    }
    __syncthreads();

    const int cg = tid & 15;
    const int rg = tid >> 4;

    float4 acc[4];
    #pragma unroll
    for (int r = 0; r < 4; ++r) acc[r] = make_float4(0.f, 0.f, 0.f, 0.f);
    float wreg[4] = {0.f, 0.f, 0.f, 0.f};

    const unsigned* vrow0 = (const unsigned*)&vs[rg * 4][cg * 4];

    #pragma unroll 4
    for (int l = 0; l < 2 * W_ + 4; ++l) {   // 0..67; max tap row rg*4+67 <= 127
        wreg[l & 3] = (l <= 2 * W_) ? wtab[l] : 0.f;
        const unsigned* p = vrow0 + (size_t)l * (CHB / 2);
        unsigned r0 = p[0], r1 = p[1];
        float4 vv;
        vv.x = bf16hi_to_f(r0 << 16);
        vv.y = bf16hi_to_f(r0 & 0xffff0000u);
        vv.z = bf16hi_to_f(r1 << 16);
        vv.w = bf16hi_to_f(r1 & 0xffff0000u);
        #pragma unroll
        for (int r = 0; r < 4; ++r) {
            float wgt = wreg[(l - r) & 3];
            acc[r].x += wgt * vv.x; acc[r].y += wgt * vv.y;
            acc[r].z += wgt * vv.z; acc[r].w += wgt * vv.w;
        }
    }

    #pragma unroll
    for (int r = 0; r < 4; ++r) {
        int nl = rg * 4 + r;
        float s = winv[nl];
        bf16x4s o = { __float2bfloat16(acc[r].x * s), __float2bfloat16(acc[r].y * s),
                      __float2bfloat16(acc[r].z * s), __float2bfloat16(acc[r].w * s) };
        *(bf16x4s*)(attn + ((size_t)b * N_ + n0 + nl) * INNER_ + h * DH_ + ch0 + cg * 4) = o;
    }
    __syncthreads();   // protect smem for caller reuse
}

// ---------------------------------------------------------------------------
// Mega-kernel: prep -> GEMM1 -> blur -> GEMM2, device-wide barriers between.
// ---------------------------------------------------------------------------
__global__ __launch_bounds__(256, 4) void mega(
    const float* __restrict__ x, const float* __restrict__ Wg,
    const float* __restrict__ Wout, const float* __restrict__ sigma,
    float* __restrict__ out,
    __hip_bfloat16* __restrict__ x_bf, __hip_bfloat16* __restrict__ Wg_t,
    __hip_bfloat16* __restrict__ Wout_t, __hip_bfloat16* __restrict__ v_bf,
    __hip_bfloat16* __restrict__ attn, unsigned* __restrict__ bar)
{
    __shared__ char smem[17408];
    const int bid = blockIdx.x;
    const int tid = threadIdx.x;

    // ---- phase 0: x cast + weight transposes ----
    {
        // x: 524288 short8-groups / 1024 blocks = 512/block, 2/thread
        #pragma unroll
        for (int p = 0; p < 2; ++p) {
            int g = bid * 512 + p * 256 + tid;
            const float4* s = (const float4*)x + (size_t)g * 2;
            float4 a = s[0], bb = s[1];
            __hip_bfloat16 o[8] = {
                __float2bfloat16(a.x),  __float2bfloat16(a.y),  __float2bfloat16(a.z),  __float2bfloat16(a.w),
                __float2bfloat16(bb.x), __float2bfloat16(bb.y), __float2bfloat16(bb.z), __float2bfloat16(bb.w)};
            *(short8*)(x_bf + (size_t)g * 8) = *(short8*)o;
        }
        if (bid < 512) {           // Wg [512,1024] -> Wg_t [1024,512]
            transpose32(Wg, Wg_t, D_, INNER_, bid >> 5, bid & 31, tid, smem);
        } else {                   // Wout [1024,512] -> Wout_t [512,1024]
            int id2 = bid - 512;
            transpose32(Wout, Wout_t, INNER_, D_, id2 >> 4, id2 & 15, tid, smem);
        }
    }
    gbar(bar + 0);

    // ---- phase 1: v = x @ Wg (bf16 out), 2048 tiles, 2/block ----
    #pragma unroll
    for (int t2 = 0; t2 < 2; ++t2) {
        int j = bid + t2 * 1024;           // 0..2047
        gemm_tile<__hip_bfloat16>(x_bf, Wg_t, v_bf, INNER_, D_, j >> 4, j & 15, tid, smem);
    }
    gbar(bar + 16);

    // ---- phase 2: banded blur, 2048 jobs, 2/block ----
    #pragma unroll
    for (int t2 = 0; t2 < 2; ++t2)
        blur_tile(v_bf, sigma, attn, bid * 2 + t2, tid, smem);
    gbar(bar + 32);

    // ---- phase 3: out = attn @ Wout (fp32 out), 1024 tiles, 1/block ----
    gemm_tile<float>(attn, Wout_t, out, D_, INNER_, bid >> 3, bid & 7, tid, smem);
}

// ---------------------------------------------------------------------------
extern "C" void kernel_launch(void* const* d_in, const int* in_sizes, int n_in,
                              void* d_out, int out_size, void* d_ws, size_t ws_size,
                              hipStream_t stream) {
    const float* x     = (const float*)d_in[0];
    const float* Wg    = (const float*)d_in[1];
    const float* Wout  = (const float*)d_in[2];
    const float* sigma = (const float*)d_in[3];
    float* out = (float*)d_out;

    char* ws = (char*)d_ws;
    __hip_bfloat16* x_bf   = (__hip_bfloat16*)ws;                           // 8 MB
    __hip_bfloat16* Wg_t   = (__hip_bfloat16*)(ws + (((size_t)8)  << 20));  // 1 MB
    __hip_bfloat16* Wout_t = (__hip_bfloat16*)(ws + (((size_t)9)  << 20));  // 1 MB
    __hip_bfloat16* v_bf   = (__hip_bfloat16*)(ws + (((size_t)10) << 20));  // 16 MB
    __hip_bfloat16* attn   = (__hip_bfloat16*)(ws + (((size_t)26) << 20));  // 16 MB
    unsigned*       bar    = (unsigned*)(ws + (((size_t)60) << 20));        // 192 B (ws >= 64 MB per r1)

    hipMemsetAsync(bar, 0, 192, stream);
    mega<<<dim3(GRID_), dim3(256), 0, stream>>>(
        x, Wg, Wout, sigma, out, x_bf, Wg_t, Wout_t, v_bf, attn, bar);
}

// Round 9
// 136.241 us; speedup vs baseline: 3.7686x; 3.7686x over previous
//
#include <hip/hip_runtime.h>
#include <hip/hip_bf16.h>
#include <math.h>

// Problem constants
#define B_ 4
#define N_ 2048
#define D_ 512
#define H_ 8
#define DH_ 128
#define INNER_ 1024   // H_*DH_
#define W_ 32         // gaussian window half-width; exp(-33^2/(2*2.5^2)) ~ 1e-38
#define M_ (B_ * N_)  // 8192

typedef __attribute__((ext_vector_type(8))) short short8;
typedef __attribute__((ext_vector_type(4))) float floatx4;

typedef const __attribute__((address_space(1))) char* gcp;
typedef __attribute__((address_space(3))) char* lcp;

__device__ __forceinline__ float bf16hi_to_f(unsigned u) {
    union { unsigned u; float f; } c; c.u = u; return c.f;
}

// ---------------------------------------------------------------------------
// bf16 MFMA GEMM, 64x64 tile / BK=64, PING-PONG double-buffered staging:
//   barrier; prefetch tile k+1 into other buffer; consume tile k.
// The compiler's vmcnt(0)-before-barrier then waits on loads that have had a
// full compute phase in flight -> drain ~0 (vs r7: drain every iter).
// smem: buf0 (A 8K | B 8K) + buf1 (A 8K | B 8K) = 32 KB; epilogue reuses buf0.
// ---------------------------------------------------------------------------
template <typename OutT>
__global__ __launch_bounds__(256, 4) void gemm_bf16_dbuf(
    const __hip_bfloat16* __restrict__ A, const __hip_bfloat16* __restrict__ Bt,
    OutT* __restrict__ C, int M, int N, int K)
{
    __shared__ char smem[32768];

    const int tid  = threadIdx.x;
    const int lane = tid & 63;
    const int w    = tid >> 6;
    const int wm   = w >> 1;
    const int wn   = w & 1;
    const int bm   = blockIdx.y;
    const int bn   = blockIdx.x;

    const int kh = lane >> 4;
    const int ml = lane & 15;

    floatx4 acc[2][2];
    #pragma unroll
    for (int i = 0; i < 2; ++i)
        #pragma unroll
        for (int j = 0; j < 2; ++j) acc[i][j] = (floatx4){0.f, 0.f, 0.f, 0.f};

    const char* Ab = (const char*)(A + (size_t)(bm * 64) * K);
    const char* Bb = (const char*)(Bt + (size_t)(bn * 64) * K);
    const size_t rowstride = (size_t)K * 2;

    // stage one 64x64 bf16 tile pair into buffer `buf` for k-offset k0
    auto issue = [&](int buf, int k0) {
        #pragma unroll
        for (int it = 0; it < 2; ++it) {
            int o = it * 4096 + tid * 16;   // wave-uniform base + lane*16
            int r = o >> 7;                 // tile row 0..63
            int s = (o >> 4) & 7;
            int c = s ^ (r & 7);            // XOR-row chunk swizzle
            size_t goff = (size_t)r * rowstride + (size_t)k0 * 2 + c * 16;
            __builtin_amdgcn_global_load_lds((gcp)(Ab + goff),
                (lcp)(smem + buf * 16384 + o), 16, 0, 0);
            __builtin_amdgcn_global_load_lds((gcp)(Bb + goff),
                (lcp)(smem + buf * 16384 + 8192 + o), 16, 0, 0);
        }
    };

    auto consume = [&](int buf) {
        const short* As = (const short*)(smem + buf * 16384);
        const short* Bs = (const short*)(smem + buf * 16384 + 8192);
        short8 af[2][2], bf[2][2];
        #pragma unroll
        for (int t = 0; t < 2; ++t) {
            int ra = wm * 32 + t * 16 + ml;
            int rb = wn * 32 + t * 16 + ml;
            #pragma unroll
            for (int kk = 0; kk < 2; ++kk) {
                int ch = kk * 4 + kh;
                af[t][kk] = *(const short8*)(As + ra * 64 + ((ch ^ (ra & 7)) * 8));
                bf[t][kk] = *(const short8*)(Bs + rb * 64 + ((ch ^ (rb & 7)) * 8));
            }
        }
        #pragma unroll
        for (int kk = 0; kk < 2; ++kk)
            #pragma unroll
            for (int i = 0; i < 2; ++i)
                #pragma unroll
                for (int j = 0; j < 2; ++j)
                    acc[i][j] = __builtin_amdgcn_mfma_f32_16x16x32_bf16(
                        af[i][kk], bf[j][kk], acc[i][j], 0, 0, 0);
    };

    const int nk = K >> 6;        // 8 (K=512) or 16 (K=1024) — always even
    issue(0, 0);
    for (int kt = 0; kt < nk; kt += 2) {
        __syncthreads();                          // drains buf0's loads
        if (kt + 1 < nk) issue(1, (kt + 1) << 6); // prefetch overlaps consume
        consume(0);
        __syncthreads();                          // drains buf1's loads
        if (kt + 2 < nk) issue(0, (kt + 2) << 6);
        consume(1);
    }
    __syncthreads();

    // ---- epilogue via LDS (vector stores) ----
    float* Cs = (float*)smem;
    const int rq = lane >> 4;
    const int cl = lane & 15;
    #pragma unroll
    for (int i = 0; i < 2; ++i)
        #pragma unroll
        for (int j = 0; j < 2; ++j)
            #pragma unroll
            for (int r = 0; r < 4; ++r)
                Cs[(wm * 32 + i * 16 + rq * 4 + r) * 64 + wn * 32 + j * 16 + cl] = acc[i][j][r];
    __syncthreads();

    if constexpr (sizeof(OutT) == 2) {
        #pragma unroll
        for (int p = 0; p < 2; ++p) {
            int idx = p * 256 + tid;
            int rr = idx >> 3;
            int cc = (idx & 7) * 8;
            const float* src = Cs + rr * 64 + cc;
            __hip_bfloat16 o[8];
            #pragma unroll
            for (int e = 0; e < 8; ++e) o[e] = __float2bfloat16(src[e]);
            *(short8*)((__hip_bfloat16*)C + (size_t)(bm * 64 + rr) * N + bn * 64 + cc) = *(short8*)o;
        }
    } else {
        #pragma unroll
        for (int p = 0; p < 4; ++p) {
            int idx = p * 256 + tid;
            int rr = idx >> 4;
            int cc = (idx & 15) * 4;
            float4 vv = *(const float4*)(Cs + rr * 64 + cc);
            *(float4*)((float*)C + (size_t)(bm * 64 + rr) * N + bn * 64 + cc) = vv;
        }
    }
}

// ---------------------------------------------------------------------------
// Fused prologue (r7): x cast + weight transposes by flat block id.
// ---------------------------------------------------------------------------
__device__ __forceinline__ void transpose32(
    const float* __restrict__ src, __hip_bfloat16* __restrict__ dst,
    int R, int Cn, int rt, int ct, int tid)
{
    __shared__ float t[32][33];
    int c0 = ct * 32, r0 = rt * 32;
    int lx = tid & 31, ly = tid >> 5;
    #pragma unroll
    for (int i = 0; i < 32; i += 8)
        t[ly + i][lx] = src[(size_t)(r0 + ly + i) * Cn + c0 + lx];
    __syncthreads();
    #pragma unroll
    for (int i = 0; i < 32; i += 8)
        dst[(size_t)(c0 + ly + i) * R + r0 + lx] = __float2bfloat16(t[lx][ly + i]);
}

__global__ __launch_bounds__(256) void prep(
    const float* __restrict__ x, const float* __restrict__ Wg,
    const float* __restrict__ Wout, __hip_bfloat16* __restrict__ x_bf,
    __hip_bfloat16* __restrict__ Wg_t, __hip_bfloat16* __restrict__ Wout_t)
{
    const int bid = blockIdx.x;
    const int tid = threadIdx.x;
    if (bid < 2048) {
        int i = bid * 256 + tid;
        const float4* s = (const float4*)x + (size_t)i * 2;
        float4 a = s[0], b = s[1];
        __hip_bfloat16 o[8] = {
            __float2bfloat16(a.x), __float2bfloat16(a.y), __float2bfloat16(a.z), __float2bfloat16(a.w),
            __float2bfloat16(b.x), __float2bfloat16(b.y), __float2bfloat16(b.z), __float2bfloat16(b.w)};
        *(short8*)(x_bf + (size_t)i * 8) = *(short8*)o;
    } else if (bid < 2560) {
        int id2 = bid - 2048;
        transpose32(Wg, Wg_t, D_, INNER_, id2 >> 5, id2 & 31, tid);
    } else {
        int id2 = bid - 2560;
        transpose32(Wout, Wout_t, INNER_, D_, id2 >> 4, id2 & 15, tid);
    }
}

// ---------------------------------------------------------------------------
// Banded gaussian blur v3 (r7): bf16 in/out, fp32 accumulate.
// ---------------------------------------------------------------------------
#define TNA 64
#define ROWSB (TNA + 2 * W_)   // 128
#define CHB 64

struct bf16x4s { __hip_bfloat16 a, b, c, d; };

__global__ __launch_bounds__(256) void banded_attn3(
    const __hip_bfloat16* __restrict__ v, const float* __restrict__ sigma,
    __hip_bfloat16* __restrict__ attn)
{
    __shared__ __hip_bfloat16 vs[ROWSB][CHB];  // 16 KB
    __shared__ float wtab[2 * W_ + 1];
    __shared__ float winv[TNA];

    const int tid = threadIdx.x;
    const int n0  = blockIdx.x * TNA;
    const int h   = blockIdx.y >> 1;
    const int ch0 = (blockIdx.y & 1) * CHB;
    const int b   = blockIdx.z;

    const __hip_bfloat16* vbase = v + (size_t)b * N_ * INNER_ + h * DH_ + ch0;
    #pragma unroll
    for (int it = 0; it < 4; ++it) {
        int idx = tid + it * 256;
        int r = idx >> 3;
        int g = idx & 7;
        int m = n0 - W_ + r;
        int4 val = make_int4(0, 0, 0, 0);
        if (m >= 0 && m < N_) val = *(const int4*)(vbase + (size_t)m * INNER_ + g * 8);
        *(int4*)&vs[r][g * 8] = val;
    }
    if (tid <= 2 * W_) {
        float sig = sigma[h];
        float d = (float)(tid - W_);
        wtab[tid] = __expf(-d * d / (2.0f * sig * sig));
    }
    __syncthreads();

    if (tid < TNA) {
        int n = n0 + tid;
        float ws = 0.f;
        #pragma unroll
        for (int j = 0; j <= 2 * W_; ++j) {
            int m = n - W_ + j;
            ws += (m >= 0 && m < N_) ? wtab[j] : 0.f;
        }
        winv[tid] = 1.0f / ws;
    }
    __syncthreads();

    const int cg = tid & 15;
    const int rg = tid >> 4;

    float4 acc[4];
    #pragma unroll
    for (int r = 0; r < 4; ++r) acc[r] = make_float4(0.f, 0.f, 0.f, 0.f);
    float wreg[4] = {0.f, 0.f, 0.f, 0.f};

    const unsigned* vrow0 = (const unsigned*)&vs[rg * 4][cg * 4];

    #pragma unroll 4
    for (int l = 0; l < 2 * W_ + 4; ++l) {   // 0..67; max tap row rg*4+67 <= 127
        wreg[l & 3] = (l <= 2 * W_) ? wtab[l] : 0.f;
        const unsigned* p = vrow0 + (size_t)l * (CHB / 2);
        unsigned r0 = p[0], r1 = p[1];
        float4 vv;
        vv.x = bf16hi_to_f(r0 << 16);
        vv.y = bf16hi_to_f(r0 & 0xffff0000u);
        vv.z = bf16hi_to_f(r1 << 16);
        vv.w = bf16hi_to_f(r1 & 0xffff0000u);
        #pragma unroll
        for (int r = 0; r < 4; ++r) {
            float wgt = wreg[(l - r) & 3];
            acc[r].x += wgt * vv.x; acc[r].y += wgt * vv.y;
            acc[r].z += wgt * vv.z; acc[r].w += wgt * vv.w;
        }
    }

    #pragma unroll
    for (int r = 0; r < 4; ++r) {
        int nl = rg * 4 + r;
        float s = winv[nl];
        bf16x4s o = { __float2bfloat16(acc[r].x * s), __float2bfloat16(acc[r].y * s),
                      __float2bfloat16(acc[r].z * s), __float2bfloat16(acc[r].w * s) };
        *(bf16x4s*)(attn + ((size_t)b * N_ + n0 + nl) * INNER_ + h * DH_ + ch0 + cg * 4) = o;
    }
}

// ---------------------------------------------------------------------------
extern "C" void kernel_launch(void* const* d_in, const int* in_sizes, int n_in,
                              void* d_out, int out_size, void* d_ws, size_t ws_size,
                              hipStream_t stream) {
    const float* x     = (const float*)d_in[0];
    const float* Wg    = (const float*)d_in[1];
    const float* Wout  = (const float*)d_in[2];
    const float* sigma = (const float*)d_in[3];
    float* out = (float*)d_out;

    char* ws = (char*)d_ws;
    __hip_bfloat16* x_bf   = (__hip_bfloat16*)ws;                           // 8 MB
    __hip_bfloat16* Wg_t   = (__hip_bfloat16*)(ws + (((size_t)8)  << 20));  // 1 MB
    __hip_bfloat16* Wout_t = (__hip_bfloat16*)(ws + (((size_t)9)  << 20));  // 1 MB
    __hip_bfloat16* v_bf   = (__hip_bfloat16*)(ws + (((size_t)10) << 20));  // 16 MB
    __hip_bfloat16* attn   = (__hip_bfloat16*)(ws + (((size_t)26) << 20));  // 16 MB

    prep<<<dim3(3072), dim3(256), 0, stream>>>(x, Wg, Wout, x_bf, Wg_t, Wout_t);

    gemm_bf16_dbuf<__hip_bfloat16><<<dim3(INNER_ / 64, M_ / 64), dim3(256), 0, stream>>>(
        x_bf, Wg_t, v_bf, M_, INNER_, D_);

    banded_attn3<<<dim3(N_ / TNA, H_ * 2, B_), dim3(256), 0, stream>>>(v_bf, sigma, attn);

    gemm_bf16_dbuf<float><<<dim3(D_ / 64, M_ / 64), dim3(256), 0, stream>>>(
        attn, Wout_t, out, M_, D_, INNER_);
}

// Round 10
// 130.187 us; speedup vs baseline: 3.9438x; 1.0465x over previous
//
#include <hip/hip_runtime.h>
#include <hip/hip_bf16.h>
#include <math.h>

// Problem constants
#define B_ 4
#define N_ 2048
#define D_ 512
#define H_ 8
#define DH_ 128
#define INNER_ 1024   // H_*DH_
#define W_ 32         // gaussian half-width; exp(-33^2/(2*2.5^2)) ~ 1e-38
#define M_ (B_ * N_)  // 8192

typedef __attribute__((ext_vector_type(8))) short short8;
typedef __attribute__((ext_vector_type(4))) float floatx4;

typedef const __attribute__((address_space(1))) char* gcp;
typedef __attribute__((address_space(3))) char* lcp;

__device__ __forceinline__ float bf16hi_to_f(unsigned u) {
    union { unsigned u; float f; } c; c.u = u; return c.f;
}
__device__ __forceinline__ unsigned f_to_bf16bits(float f) {
    union { float f; unsigned u; } c; c.f = f;
    return (c.u + 0x7fffu + ((c.u >> 16) & 1u)) >> 16;   // RNE
}

struct bf16x4s { __hip_bfloat16 a, b, c, d; };

// ---------------------------------------------------------------------------
// FUSED GEMM1 + banded gaussian blur.
// Block = (bm in 128 row-tiles of 64, h in 8 heads). Computes the 128-row
// (64-overlap) x 128-ch v-tile = x_bf[n0-32..n0+96, :] @ Wg_h^T via MFMA
// (acc 4x4 floatx4 / wave, 2x2 waves of 64x64), dumps it to LDS as bf16
// (cols pair-packed -> per-head channel PERMUTATION, compensated by
// permuting Wout_t columns in prep), blurs rows (65-tap, batch-masked,
// row-normalized), writes attn[64 rows x 128 stored-ch].
// v never touches HBM.
// ---------------------------------------------------------------------------
__global__ __launch_bounds__(256, 4) void g1_blur(
    const __hip_bfloat16* __restrict__ x_bf,   // [8192, 512]
    const __hip_bfloat16* __restrict__ Wg_t,   // [1024, 512]
    const float* __restrict__ sigma,           // [8]
    __hip_bfloat16* __restrict__ attn)         // [8192, 1024] (perm-ch)
{
    __shared__ char smem[33824];  // phase1: A 16K | B 16K; phase2: vs 33280 + wtab + winv
    __hip_bfloat16* Asm = (__hip_bfloat16*)smem;
    __hip_bfloat16* Bsm = (__hip_bfloat16*)(smem + 16384);

    const int tid  = threadIdx.x;
    const int lane = tid & 63;
    const int w    = tid >> 6;
    const int wm   = w >> 1;        // 0..1 (row half)
    const int wn   = w & 1;         // 0..1 (col half)
    const int quad = lane >> 4;     // 0..3
    const int cl   = lane & 15;
    const int bm   = blockIdx.x;    // 0..127
    const int h    = blockIdx.y;    // 0..7
    const int n0   = bm * 64;
    const int nb0  = n0 & (N_ - 1); // row offset within batch

    floatx4 acc[4][4];
    #pragma unroll
    for (int i = 0; i < 4; ++i)
        #pragma unroll
        for (int j = 0; j < 4; ++j) acc[i][j] = (floatx4){0.f, 0.f, 0.f, 0.f};

    const char* Ab = (const char*)x_bf;                              // stride 1024 B
    const char* Bb = (const char*)(Wg_t + (size_t)(h * DH_) * D_);   // stride 1024 B

    for (int k0 = 0; k0 < D_; k0 += 64) {
        // ---- stage A (128 rows, clamped) and B (128 ch rows), 64 k each ----
        #pragma unroll
        for (int it = 0; it < 4; ++it) {
            int o = it * 4096 + tid * 16;   // LDS byte, lane-linear within wave
            int r = o >> 7;                 // 0..127
            int s = (o >> 4) & 7;
            int c = s ^ (r & 7);            // XOR-row chunk swizzle
            int gr = n0 - W_ + r;
            gr = gr < 0 ? 0 : (gr > M_ - 1 ? M_ - 1 : gr);   // clamp (masked later)
            __builtin_amdgcn_global_load_lds(
                (gcp)(Ab + (size_t)gr * 1024 + k0 * 2 + c * 16), (lcp)(smem + o), 16, 0, 0);
            __builtin_amdgcn_global_load_lds(
                (gcp)(Bb + (size_t)r * 1024 + k0 * 2 + c * 16), (lcp)(smem + 16384 + o), 16, 0, 0);
        }
        __syncthreads();

        const short* As = (const short*)Asm;
        const short* Bs = (const short*)Bsm;
        #pragma unroll
        for (int kk = 0; kk < 2; ++kk) {
            short8 af[4], bf[4];
            int ch = kk * 4 + quad;         // 16B chunk (8 k) within 64-k row
            #pragma unroll
            for (int t = 0; t < 4; ++t) {
                int ra = wm * 64 + t * 16 + cl;
                int rb = wn * 64 + t * 16 + cl;
                af[t] = *(const short8*)(As + ra * 64 + ((ch ^ (ra & 7)) * 8));
                bf[t] = *(const short8*)(Bs + rb * 64 + ((ch ^ (rb & 7)) * 8));
            }
            #pragma unroll
            for (int i = 0; i < 4; ++i)
                #pragma unroll
                for (int j = 0; j < 4; ++j)
                    acc[i][j] = __builtin_amdgcn_mfma_f32_16x16x32_bf16(
                        af[i], bf[j], acc[i][j], 0, 0, 0);
        }
        __syncthreads();
    }

    // ---- dump v-tile to LDS bf16, pair-packed cols (stride 130 shorts) ----
    // C/D: row = wm*64 + i*16 + quad*4 + r ; true col = wn*64 + j*16 + cl.
    // stored col = wn*64 + (j>>1)*32 + cl*2 + (j&1)  [perm matches prep-Wout]
    unsigned short* vsp = (unsigned short*)smem;
    float* wtab = (float*)(smem + 33280);        // 65 floats
    float* winv = (float*)(smem + 33280 + 272);  // 64 floats

    #pragma unroll
    for (int i = 0; i < 4; ++i) {
        #pragma unroll
        for (int jp = 0; jp < 2; ++jp) {
            #pragma unroll
            for (int rr = 0; rr < 4; ++rr) {
                int srow = wm * 64 + i * 16 + quad * 4 + rr;
                int vb = nb0 - W_ + srow;                 // batch-local tap row
                unsigned u = 0u;
                if (vb >= 0 && vb < N_) {
                    unsigned lo = f_to_bf16bits(acc[i][jp * 2][rr]);
                    unsigned hi = f_to_bf16bits(acc[i][jp * 2 + 1][rr]);
                    u = lo | (hi << 16);
                }
                int scol = wn * 64 + jp * 32 + cl * 2;
                *(unsigned*)(vsp + srow * 130 + scol) = u;
            }
        }
    }
    if (tid <= 2 * W_) {
        float sig = sigma[h];
        float d = (float)(tid - W_);
        wtab[tid] = __expf(-d * d / (2.0f * sig * sig));
    }
    __syncthreads();

    if (tid < 64) {
        int nbl = nb0 + tid;
        float ws = 0.f;
        #pragma unroll
        for (int j = 0; j <= 2 * W_; ++j) {
            int m = nbl - W_ + j;
            ws += (m >= 0 && m < N_) ? wtab[j] : 0.f;
        }
        winv[tid] = 1.0f / ws;
    }

    // ---- blur: thread = 4 stored-ch x 8 rows, rolling 8-reg window ----
    const int cg = tid & 31;   // stored-ch group (4 ch)
    const int rg = tid >> 5;   // 0..7 (8 out rows each)

    float4 bacc[8];
    #pragma unroll
    for (int r = 0; r < 8; ++r) bacc[r] = make_float4(0.f, 0.f, 0.f, 0.f);
    float wreg[8] = {0.f, 0.f, 0.f, 0.f, 0.f, 0.f, 0.f, 0.f};

    const unsigned* vrow0 = (const unsigned*)(vsp + rg * 8 * 130 + cg * 4);

    // out row o = rg*8+rr needs vs rows o..o+64, weight wtab[l-rr]; max l = 71.
    #pragma unroll 8
    for (int l = 0; l < 2 * W_ + 8; ++l) {   // 0..71; vs row rg*8+l <= 127
        wreg[l & 7] = (l <= 2 * W_) ? wtab[l] : 0.f;
        const unsigned* p = vrow0 + (size_t)l * 65;   // 130 shorts = 65 u32
        unsigned r0 = p[0], r1 = p[1];
        float4 vv;
        vv.x = bf16hi_to_f(r0 << 16);
        vv.y = bf16hi_to_f(r0 & 0xffff0000u);
        vv.z = bf16hi_to_f(r1 << 16);
        vv.w = bf16hi_to_f(r1 & 0xffff0000u);
        #pragma unroll
        for (int r = 0; r < 8; ++r) {
            float wgt = wreg[(l - r) & 7];
            bacc[r].x += wgt * vv.x; bacc[r].y += wgt * vv.y;
            bacc[r].z += wgt * vv.z; bacc[r].w += wgt * vv.w;
        }
    }
    __syncthreads();   // winv ready

    #pragma unroll
    for (int r = 0; r < 8; ++r) {
        int o = rg * 8 + r;
        float s = winv[o];
        bf16x4s ov = { __float2bfloat16(bacc[r].x * s), __float2bfloat16(bacc[r].y * s),
                       __float2bfloat16(bacc[r].z * s), __float2bfloat16(bacc[r].w * s) };
        *(bf16x4s*)(attn + (size_t)(n0 + o) * INNER_ + h * DH_ + cg * 4) = ov;
    }
}

// ---------------------------------------------------------------------------
// bf16 MFMA GEMM (r9 dbuf, 64x64/BK=64) for GEMM2: out = attn @ Wout_t^T.
// ---------------------------------------------------------------------------
template <typename OutT>
__global__ __launch_bounds__(256, 4) void gemm_bf16_dbuf(
    const __hip_bfloat16* __restrict__ A, const __hip_bfloat16* __restrict__ Bt,
    OutT* __restrict__ C, int M, int N, int K)
{
    __shared__ char smem[32768];

    const int tid  = threadIdx.x;
    const int lane = tid & 63;
    const int w    = tid >> 6;
    const int wm   = w >> 1;
    const int wn   = w & 1;
    const int bm   = blockIdx.y;
    const int bn   = blockIdx.x;

    const int kh = lane >> 4;
    const int ml = lane & 15;

    floatx4 acc[2][2];
    #pragma unroll
    for (int i = 0; i < 2; ++i)
        #pragma unroll
        for (int j = 0; j < 2; ++j) acc[i][j] = (floatx4){0.f, 0.f, 0.f, 0.f};

    const char* Ab = (const char*)(A + (size_t)(bm * 64) * K);
    const char* Bb = (const char*)(Bt + (size_t)(bn * 64) * K);
    const size_t rowstride = (size_t)K * 2;

    auto issue = [&](int buf, int k0) {
        #pragma unroll
        for (int it = 0; it < 2; ++it) {
            int o = it * 4096 + tid * 16;
            int r = o >> 7;
            int s = (o >> 4) & 7;
            int c = s ^ (r & 7);
            size_t goff = (size_t)r * rowstride + (size_t)k0 * 2 + c * 16;
            __builtin_amdgcn_global_load_lds((gcp)(Ab + goff),
                (lcp)(smem + buf * 16384 + o), 16, 0, 0);
            __builtin_amdgcn_global_load_lds((gcp)(Bb + goff),
                (lcp)(smem + buf * 16384 + 8192 + o), 16, 0, 0);
        }
    };
    auto consume = [&](int buf) {
        const short* As = (const short*)(smem + buf * 16384);
        const short* Bs = (const short*)(smem + buf * 16384 + 8192);
        short8 af[2][2], bf[2][2];
        #pragma unroll
        for (int t = 0; t < 2; ++t) {
            int ra = wm * 32 + t * 16 + ml;
            int rb = wn * 32 + t * 16 + ml;
            #pragma unroll
            for (int kk = 0; kk < 2; ++kk) {
                int ch = kk * 4 + kh;
                af[t][kk] = *(const short8*)(As + ra * 64 + ((ch ^ (ra & 7)) * 8));
                bf[t][kk] = *(const short8*)(Bs + rb * 64 + ((ch ^ (rb & 7)) * 8));
            }
        }
        #pragma unroll
        for (int kk = 0; kk < 2; ++kk)
            #pragma unroll
            for (int i = 0; i < 2; ++i)
                #pragma unroll
                for (int j = 0; j < 2; ++j)
                    acc[i][j] = __builtin_amdgcn_mfma_f32_16x16x32_bf16(
                        af[i][kk], bf[j][kk], acc[i][j], 0, 0, 0);
    };

    const int nk = K >> 6;
    issue(0, 0);
    for (int kt = 0; kt < nk; kt += 2) {
        __syncthreads();
        if (kt + 1 < nk) issue(1, (kt + 1) << 6);
        consume(0);
        __syncthreads();
        if (kt + 2 < nk) issue(0, (kt + 2) << 6);
        consume(1);
    }
    __syncthreads();

    float* Cs = (float*)smem;
    const int rq = lane >> 4;
    const int cl = lane & 15;
    #pragma unroll
    for (int i = 0; i < 2; ++i)
        #pragma unroll
        for (int j = 0; j < 2; ++j)
            #pragma unroll
            for (int r = 0; r < 4; ++r)
                Cs[(wm * 32 + i * 16 + rq * 4 + r) * 64 + wn * 32 + j * 16 + cl] = acc[i][j][r];
    __syncthreads();

    if constexpr (sizeof(OutT) == 2) {
        #pragma unroll
        for (int p = 0; p < 2; ++p) {
            int idx = p * 256 + tid;
            int rr = idx >> 3;
            int cc = (idx & 7) * 8;
            const float* src = Cs + rr * 64 + cc;
            __hip_bfloat16 o[8];
            #pragma unroll
            for (int e = 0; e < 8; ++e) o[e] = __float2bfloat16(src[e]);
            *(short8*)((__hip_bfloat16*)C + (size_t)(bm * 64 + rr) * N + bn * 64 + cc) = *(short8*)o;
        }
    } else {
        #pragma unroll
        for (int p = 0; p < 4; ++p) {
            int idx = p * 256 + tid;
            int rr = idx >> 4;
            int cc = (idx & 15) * 4;
            float4 vv = *(const float4*)(Cs + rr * 64 + cc);
            *(float4*)((float*)C + (size_t)(bm * 64 + rr) * N + bn * 64 + cc) = vv;
        }
    }
}

// ---------------------------------------------------------------------------
// Fused prologue: x cast + Wg transpose + Wout transpose WITH column perm.
// perm within each head-128: c -> wn*64 + (j>>1)*32 + cl*2 + (j&1); for a
// 32-aligned span this is newcol = r0 + (lx&15)*2 + (lx>>4).
// ---------------------------------------------------------------------------
template <bool PERM>
__device__ __forceinline__ void transpose32p(
    const float* __restrict__ src, __hip_bfloat16* __restrict__ dst,
    int R, int Cn, int rt, int ct, int tid)
{
    __shared__ float t[32][33];
    int c0 = ct * 32, r0 = rt * 32;
    int lx = tid & 31, ly = tid >> 5;
    #pragma unroll
    for (int i = 0; i < 32; i += 8)
        t[ly + i][lx] = src[(size_t)(r0 + ly + i) * Cn + c0 + lx];
    __syncthreads();
    int colx = PERM ? (r0 + ((lx & 15) * 2 | (lx >> 4))) : (r0 + lx);
    #pragma unroll
    for (int i = 0; i < 32; i += 8)
        dst[(size_t)(c0 + ly + i) * R + colx] = __float2bfloat16(t[lx][ly + i]);
}

__global__ __launch_bounds__(256) void prep(
    const float* __restrict__ x, const float* __restrict__ Wg,
    const float* __restrict__ Wout, __hip_bfloat16* __restrict__ x_bf,
    __hip_bfloat16* __restrict__ Wg_t, __hip_bfloat16* __restrict__ Wout_t)
{
    const int bid = blockIdx.x;
    const int tid = threadIdx.x;
    if (bid < 2048) {
        int i = bid * 256 + tid;
        const float4* s = (const float4*)x + (size_t)i * 2;
        float4 a = s[0], b = s[1];
        __hip_bfloat16 o[8] = {
            __float2bfloat16(a.x), __float2bfloat16(a.y), __float2bfloat16(a.z), __float2bfloat16(a.w),
            __float2bfloat16(b.x), __float2bfloat16(b.y), __float2bfloat16(b.z), __float2bfloat16(b.w)};
        *(short8*)(x_bf + (size_t)i * 8) = *(short8*)o;
    } else if (bid < 2560) {
        int id2 = bid - 2048;   // Wg [512,1024] -> Wg_t [1024,512]
        transpose32p<false>(Wg, Wg_t, D_, INNER_, id2 >> 5, id2 & 31, tid);
    } else {
        int id2 = bid - 2560;   // Wout [1024,512] -> Wout_t [512,1024], perm cols
        transpose32p<true>(Wout, Wout_t, INNER_, D_, id2 >> 4, id2 & 15, tid);
    }
}

// ---------------------------------------------------------------------------
extern "C" void kernel_launch(void* const* d_in, const int* in_sizes, int n_in,
                              void* d_out, int out_size, void* d_ws, size_t ws_size,
                              hipStream_t stream) {
    const float* x     = (const float*)d_in[0];
    const float* Wg    = (const float*)d_in[1];
    const float* Wout  = (const float*)d_in[2];
    const float* sigma = (const float*)d_in[3];
    float* out = (float*)d_out;

    char* ws = (char*)d_ws;
    __hip_bfloat16* x_bf   = (__hip_bfloat16*)ws;                           // 8 MB
    __hip_bfloat16* Wg_t   = (__hip_bfloat16*)(ws + (((size_t)8)  << 20));  // 1 MB
    __hip_bfloat16* Wout_t = (__hip_bfloat16*)(ws + (((size_t)9)  << 20));  // 1 MB (perm cols)
    __hip_bfloat16* attn   = (__hip_bfloat16*)(ws + (((size_t)10) << 20));  // 16 MB (perm ch)

    prep<<<dim3(3072), dim3(256), 0, stream>>>(x, Wg, Wout, x_bf, Wg_t, Wout_t);

    // fused v-GEMM + blur: grid 128 row-tiles x 8 heads = 1024 blocks
    g1_blur<<<dim3(M_ / 64, H_), dim3(256), 0, stream>>>(x_bf, Wg_t, sigma, attn);

    // out = attn @ Wout (perm-consistent): grid 8 x 128 = 1024 blocks
    gemm_bf16_dbuf<float><<<dim3(D_ / 64, M_ / 64), dim3(256), 0, stream>>>(
        attn, Wout_t, out, M_, D_, INNER_);
}

// Round 11
// 118.797 us; speedup vs baseline: 4.3220x; 1.0959x over previous
//
#include <hip/hip_runtime.h>
#include <hip/hip_bf16.h>
#include <math.h>

// Problem constants
#define B_ 4
#define N_ 2048
#define D_ 512
#define H_ 8
#define DH_ 128
#define INNER_ 1024   // H_*DH_
#define W_ 32         // gaussian half-width; exp(-33^2/(2*2.5^2)) ~ 1e-38
#define M_ (B_ * N_)  // 8192

typedef __attribute__((ext_vector_type(8))) short short8;
typedef __attribute__((ext_vector_type(4))) float floatx4;

typedef const __attribute__((address_space(1))) char* gcp;
typedef __attribute__((address_space(3))) char* lcp;

__device__ __forceinline__ unsigned f_to_bf16bits(float f) {
    union { float f; unsigned u; } c; c.f = f;
    return (c.u + 0x7fffu + ((c.u >> 16) & 1u)) >> 16;   // RNE
}
__device__ __forceinline__ float bf16s_to_f(unsigned short s) {
    union { unsigned u; float f; } c; c.u = ((unsigned)s) << 16; return c.f;
}

// ---------------------------------------------------------------------------
// FUSED GEMM1 + banded gaussian blur (blur as MFMA).
// Block = (64-out-row tile, head). Phase 1: v-tile[128 rows x 128 ch] =
// x_bf[n0-32 .. n0+96) @ Wg_h^T via MFMA (r10 structure). Phase 2: dump acc
// TRANSPOSED to LDS vsT[ch][row] bf16 (batch-masked), build per-thread Band
// A-frags from bf16-rounded wtab in registers, then
// attn[64x128] = Band(64x128) @ vsT^T via 32 MFMAs/wave; row-normalize with
// winv summed over the SAME bf16 weights; store true-channel layout.
// LDS 35.3 KB -> 4 blocks/CU.
// ---------------------------------------------------------------------------
#define VST 136   // vsT row stride in shorts (272 B: 16B-aligned, ~4-way max)

__global__ __launch_bounds__(256, 4) void g1_blur(
    const __hip_bfloat16* __restrict__ x_bf,   // [8192, 512]
    const __hip_bfloat16* __restrict__ Wg_t,   // [1024, 512]
    const float* __restrict__ sigma,           // [8]
    __hip_bfloat16* __restrict__ attn)         // [8192, 1024]
{
    __shared__ char smem[35328];
    // phase1: A-tile 16K @0 | B-tile 16K @16384
    // phase2: vsT[128][VST] shorts 34816 @0 | wtabS 130B @34816 | winv 256B @35072
    __hip_bfloat16* Asm = (__hip_bfloat16*)smem;
    __hip_bfloat16* Bsm = (__hip_bfloat16*)(smem + 16384);

    const int tid  = threadIdx.x;
    const int lane = tid & 63;
    const int w    = tid >> 6;
    const int wm   = w >> 1;        // 0..1
    const int wn   = w & 1;         // 0..1
    const int quad = lane >> 4;     // 0..3
    const int cl   = lane & 15;
    const int bm   = blockIdx.x;    // 0..127
    const int h    = blockIdx.y;    // 0..7
    const int n0   = bm * 64;
    const int nb0  = n0 & (N_ - 1); // row offset within batch

    floatx4 acc[4][4];
    #pragma unroll
    for (int i = 0; i < 4; ++i)
        #pragma unroll
        for (int j = 0; j < 4; ++j) acc[i][j] = (floatx4){0.f, 0.f, 0.f, 0.f};

    const char* Ab = (const char*)x_bf;                              // stride 1024 B
    const char* Bb = (const char*)(Wg_t + (size_t)(h * DH_) * D_);   // stride 1024 B

    for (int k0 = 0; k0 < D_; k0 += 64) {
        #pragma unroll
        for (int it = 0; it < 4; ++it) {
            int o = it * 4096 + tid * 16;   // wave-uniform base + lane*16
            int r = o >> 7;                 // 0..127
            int s = (o >> 4) & 7;
            int c = s ^ (r & 7);            // XOR-row chunk swizzle
            int gr = n0 - W_ + r;
            gr = gr < 0 ? 0 : (gr > M_ - 1 ? M_ - 1 : gr);   // clamp (masked later)
            __builtin_amdgcn_global_load_lds(
                (gcp)(Ab + (size_t)gr * 1024 + k0 * 2 + c * 16), (lcp)(smem + o), 16, 0, 0);
            __builtin_amdgcn_global_load_lds(
                (gcp)(Bb + (size_t)r * 1024 + k0 * 2 + c * 16), (lcp)(smem + 16384 + o), 16, 0, 0);
        }
        __syncthreads();

        const short* As = (const short*)Asm;
        const short* Bs = (const short*)Bsm;
        #pragma unroll
        for (int kk = 0; kk < 2; ++kk) {
            short8 af[4], bf[4];
            int ch = kk * 4 + quad;
            #pragma unroll
            for (int t = 0; t < 4; ++t) {
                int ra = wm * 64 + t * 16 + cl;
                int rb = wn * 64 + t * 16 + cl;
                af[t] = *(const short8*)(As + ra * 64 + ((ch ^ (ra & 7)) * 8));
                bf[t] = *(const short8*)(Bs + rb * 64 + ((ch ^ (rb & 7)) * 8));
            }
            #pragma unroll
            for (int i = 0; i < 4; ++i)
                #pragma unroll
                for (int j = 0; j < 4; ++j)
                    acc[i][j] = __builtin_amdgcn_mfma_f32_16x16x32_bf16(
                        af[i], bf[j], acc[i][j], 0, 0, 0);
        }
        __syncthreads();
    }

    // ---- phase 2 setup: dump v-tile TRANSPOSED vsT[ch][row], batch-masked ----
    unsigned short* vsT   = (unsigned short*)smem;
    unsigned short* wtabS = (unsigned short*)(smem + 34816);   // 65 bf16
    float*          winv  = (float*)(smem + 35072);            // 64 f32

    #pragma unroll
    for (int i = 0; i < 4; ++i) {
        #pragma unroll
        for (int j = 0; j < 4; ++j) {
            int ch   = wn * 64 + j * 16 + cl;
            int row0 = wm * 64 + i * 16 + quad * 4;     // 4 consecutive rows
            unsigned p01 = 0u, p23 = 0u;
            #pragma unroll
            for (int rr = 0; rr < 4; ++rr) {
                int vb = nb0 - W_ + row0 + rr;
                unsigned bits = (vb >= 0 && vb < N_) ? f_to_bf16bits(acc[i][j][rr]) : 0u;
                if (rr < 2) p01 |= bits << (rr * 16);
                else        p23 |= bits << ((rr - 2) * 16);
            }
            unsigned* dst = (unsigned*)(vsT + ch * VST + row0);
            dst[0] = p01; dst[1] = p23;
        }
    }
    if (tid <= 2 * W_) {
        float sig = sigma[h];
        float d = (float)(tid - W_);
        wtabS[tid] = (unsigned short)f_to_bf16bits(__expf(-d * d / (2.0f * sig * sig)));
    }
    __syncthreads();

    if (tid < 64) {
        float ws = 0.f;
        #pragma unroll
        for (int l = 0; l <= 2 * W_; ++l) {
            int vb = nb0 + tid + l - W_;
            ws += (vb >= 0 && vb < N_) ? bf16s_to_f(wtabS[l]) : 0.f;
        }
        winv[tid] = 1.0f / ws;
    }

    // Band A-frags in registers: afr[mi][k0] elem j = wtab[k - row],
    // k = k0*32 + quad*8 + j, row = wm*32 + mi*16 + cl.
    short afr[2][4][8];
    #pragma unroll
    for (int mi = 0; mi < 2; ++mi) {
        int row = wm * 32 + mi * 16 + cl;
        #pragma unroll
        for (int k4 = 0; k4 < 4; ++k4) {
            int lb = k4 * 32 + quad * 8 - row;
            #pragma unroll
            for (int j = 0; j < 8; ++j) {
                int l = lb + j;
                afr[mi][k4][j] = (l >= 0 && l <= 2 * W_) ? (short)wtabS[l] : (short)0;
            }
        }
    }
    __syncthreads();

    // ---- blur MFMA: out[64 x 128] = Band @ vsT^T ----
    floatx4 oacc[2][4];
    #pragma unroll
    for (int mi = 0; mi < 2; ++mi)
        #pragma unroll
        for (int ni = 0; ni < 4; ++ni) oacc[mi][ni] = (floatx4){0.f, 0.f, 0.f, 0.f};

    #pragma unroll
    for (int k4 = 0; k4 < 4; ++k4) {
        short8 bfr[4];
        #pragma unroll
        for (int ni = 0; ni < 4; ++ni) {
            int ch = wn * 64 + ni * 16 + cl;
            bfr[ni] = *(const short8*)((const short*)vsT + ch * VST + k4 * 32 + quad * 8);
        }
        #pragma unroll
        for (int mi = 0; mi < 2; ++mi)
            #pragma unroll
            for (int ni = 0; ni < 4; ++ni)
                oacc[mi][ni] = __builtin_amdgcn_mfma_f32_16x16x32_bf16(
                    *(short8*)afr[mi][k4], bfr[ni], oacc[mi][ni], 0, 0, 0);
    }

    // ---- normalize + store (true channel order) ----
    float wv[2][4];
    #pragma unroll
    for (int mi = 0; mi < 2; ++mi)
        #pragma unroll
        for (int r = 0; r < 4; ++r)
            wv[mi][r] = winv[wm * 32 + mi * 16 + quad * 4 + r];

    #pragma unroll
    for (int mi = 0; mi < 2; ++mi) {
        #pragma unroll
        for (int ni = 0; ni < 4; ++ni) {
            int ch = wn * 64 + ni * 16 + cl;
            #pragma unroll
            for (int r = 0; r < 4; ++r) {
                int orow = wm * 32 + mi * 16 + quad * 4 + r;
                attn[(size_t)(n0 + orow) * INNER_ + h * DH_ + ch] =
                    __float2bfloat16(oacc[mi][ni][r] * wv[mi][r]);
            }
        }
    }
}

// ---------------------------------------------------------------------------
// bf16 MFMA GEMM (r9 dbuf, 64x64/BK=64) for GEMM2.
// ---------------------------------------------------------------------------
template <typename OutT>
__global__ __launch_bounds__(256, 4) void gemm_bf16_dbuf(
    const __hip_bfloat16* __restrict__ A, const __hip_bfloat16* __restrict__ Bt,
    OutT* __restrict__ C, int M, int N, int K)
{
    __shared__ char smem[32768];

    const int tid  = threadIdx.x;
    const int lane = tid & 63;
    const int w    = tid >> 6;
    const int wm   = w >> 1;
    const int wn   = w & 1;
    const int bm   = blockIdx.y;
    const int bn   = blockIdx.x;

    const int kh = lane >> 4;
    const int ml = lane & 15;

    floatx4 acc[2][2];
    #pragma unroll
    for (int i = 0; i < 2; ++i)
        #pragma unroll
        for (int j = 0; j < 2; ++j) acc[i][j] = (floatx4){0.f, 0.f, 0.f, 0.f};

    const char* Ab = (const char*)(A + (size_t)(bm * 64) * K);
    const char* Bb = (const char*)(Bt + (size_t)(bn * 64) * K);
    const size_t rowstride = (size_t)K * 2;

    auto issue = [&](int buf, int k0) {
        #pragma unroll
        for (int it = 0; it < 2; ++it) {
            int o = it * 4096 + tid * 16;
            int r = o >> 7;
            int s = (o >> 4) & 7;
            int c = s ^ (r & 7);
            size_t goff = (size_t)r * rowstride + (size_t)k0 * 2 + c * 16;
            __builtin_amdgcn_global_load_lds((gcp)(Ab + goff),
                (lcp)(smem + buf * 16384 + o), 16, 0, 0);
            __builtin_amdgcn_global_load_lds((gcp)(Bb + goff),
                (lcp)(smem + buf * 16384 + 8192 + o), 16, 0, 0);
        }
    };
    auto consume = [&](int buf) {
        const short* As = (const short*)(smem + buf * 16384);
        const short* Bs = (const short*)(smem + buf * 16384 + 8192);
        short8 af[2][2], bf[2][2];
        #pragma unroll
        for (int t = 0; t < 2; ++t) {
            int ra = wm * 32 + t * 16 + ml;
            int rb = wn * 32 + t * 16 + ml;
            #pragma unroll
            for (int kk = 0; kk < 2; ++kk) {
                int ch = kk * 4 + kh;
                af[t][kk] = *(const short8*)(As + ra * 64 + ((ch ^ (ra & 7)) * 8));
                bf[t][kk] = *(const short8*)(Bs + rb * 64 + ((ch ^ (rb & 7)) * 8));
            }
        }
        #pragma unroll
        for (int kk = 0; kk < 2; ++kk)
            #pragma unroll
            for (int i = 0; i < 2; ++i)
                #pragma unroll
                for (int j = 0; j < 2; ++j)
                    acc[i][j] = __builtin_amdgcn_mfma_f32_16x16x32_bf16(
                        af[i][kk], bf[j][kk], acc[i][j], 0, 0, 0);
    };

    const int nk = K >> 6;
    issue(0, 0);
    for (int kt = 0; kt < nk; kt += 2) {
        __syncthreads();
        if (kt + 1 < nk) issue(1, (kt + 1) << 6);
        consume(0);
        __syncthreads();
        if (kt + 2 < nk) issue(0, (kt + 2) << 6);
        consume(1);
    }
    __syncthreads();

    float* Cs = (float*)smem;
    const int rq = lane >> 4;
    const int cl = lane & 15;
    #pragma unroll
    for (int i = 0; i < 2; ++i)
        #pragma unroll
        for (int j = 0; j < 2; ++j)
            #pragma unroll
            for (int r = 0; r < 4; ++r)
                Cs[(wm * 32 + i * 16 + rq * 4 + r) * 64 + wn * 32 + j * 16 + cl] = acc[i][j][r];
    __syncthreads();

    if constexpr (sizeof(OutT) == 2) {
        #pragma unroll
        for (int p = 0; p < 2; ++p) {
            int idx = p * 256 + tid;
            int rr = idx >> 3;
            int cc = (idx & 7) * 8;
            const float* src = Cs + rr * 64 + cc;
            __hip_bfloat16 o[8];
            #pragma unroll
            for (int e = 0; e < 8; ++e) o[e] = __float2bfloat16(src[e]);
            *(short8*)((__hip_bfloat16*)C + (size_t)(bm * 64 + rr) * N + bn * 64 + cc) = *(short8*)o;
        }
    } else {
        #pragma unroll
        for (int p = 0; p < 4; ++p) {
            int idx = p * 256 + tid;
            int rr = idx >> 4;
            int cc = (idx & 15) * 4;
            float4 vv = *(const float4*)(Cs + rr * 64 + cc);
            *(float4*)((float*)C + (size_t)(bm * 64 + rr) * N + bn * 64 + cc) = vv;
        }
    }
}

// ---------------------------------------------------------------------------
// Fused prologue: x cast + plain weight transposes (no perm).
// ---------------------------------------------------------------------------
__device__ __forceinline__ void transpose32(
    const float* __restrict__ src, __hip_bfloat16* __restrict__ dst,
    int R, int Cn, int rt, int ct, int tid)
{
    __shared__ float t[32][33];
    int c0 = ct * 32, r0 = rt * 32;
    int lx = tid & 31, ly = tid >> 5;
    #pragma unroll
    for (int i = 0; i < 32; i += 8)
        t[ly + i][lx] = src[(size_t)(r0 + ly + i) * Cn + c0 + lx];
    __syncthreads();
    #pragma unroll
    for (int i = 0; i < 32; i += 8)
        dst[(size_t)(c0 + ly + i) * R + r0 + lx] = __float2bfloat16(t[lx][ly + i]);
}

__global__ __launch_bounds__(256) void prep(
    const float* __restrict__ x, const float* __restrict__ Wg,
    const float* __restrict__ Wout, __hip_bfloat16* __restrict__ x_bf,
    __hip_bfloat16* __restrict__ Wg_t, __hip_bfloat16* __restrict__ Wout_t)
{
    const int bid = blockIdx.x;
    const int tid = threadIdx.x;
    if (bid < 2048) {
        int i = bid * 256 + tid;
        const float4* s = (const float4*)x + (size_t)i * 2;
        float4 a = s[0], b = s[1];
        __hip_bfloat16 o[8] = {
            __float2bfloat16(a.x), __float2bfloat16(a.y), __float2bfloat16(a.z), __float2bfloat16(a.w),
            __float2bfloat16(b.x), __float2bfloat16(b.y), __float2bfloat16(b.z), __float2bfloat16(b.w)};
        *(short8*)(x_bf + (size_t)i * 8) = *(short8*)o;
    } else if (bid < 2560) {
        int id2 = bid - 2048;   // Wg [512,1024] -> Wg_t [1024,512]
        transpose32(Wg, Wg_t, D_, INNER_, id2 >> 5, id2 & 31, tid);
    } else {
        int id2 = bid - 2560;   // Wout [1024,512] -> Wout_t [512,1024]
        transpose32(Wout, Wout_t, INNER_, D_, id2 >> 4, id2 & 15, tid);
    }
}

// ---------------------------------------------------------------------------
extern "C" void kernel_launch(void* const* d_in, const int* in_sizes, int n_in,
                              void* d_out, int out_size, void* d_ws, size_t ws_size,
                              hipStream_t stream) {
    const float* x     = (const float*)d_in[0];
    const float* Wg    = (const float*)d_in[1];
    const float* Wout  = (const float*)d_in[2];
    const float* sigma = (const float*)d_in[3];
    float* out = (float*)d_out;

    char* ws = (char*)d_ws;
    __hip_bfloat16* x_bf   = (__hip_bfloat16*)ws;                           // 8 MB
    __hip_bfloat16* Wg_t   = (__hip_bfloat16*)(ws + (((size_t)8)  << 20));  // 1 MB
    __hip_bfloat16* Wout_t = (__hip_bfloat16*)(ws + (((size_t)9)  << 20));  // 1 MB
    __hip_bfloat16* attn   = (__hip_bfloat16*)(ws + (((size_t)10) << 20));  // 16 MB

    prep<<<dim3(3072), dim3(256), 0, stream>>>(x, Wg, Wout, x_bf, Wg_t, Wout_t);

    // fused v-GEMM + MFMA-blur: 128 row-tiles x 8 heads = 1024 blocks
    g1_blur<<<dim3(M_ / 64, H_), dim3(256), 0, stream>>>(x_bf, Wg_t, sigma, attn);

    // out = attn @ Wout : 8 x 128 = 1024 blocks
    gemm_bf16_dbuf<float><<<dim3(D_ / 64, M_ / 64), dim3(256), 0, stream>>>(
        attn, Wout_t, out, M_, D_, INNER_);
}